// Round 1
// baseline (1431.720 us; speedup 1.0000x reference)
//
#include <hip/hip_runtime.h>
#include <hip/hip_bf16.h>
#include <stdint.h>

#pragma clang fp contract(off)

#define FH 512
#define FW 512
#define NA 9
#define HW (FH*FW)
#define TOTAL (HW*NA)
#define PRE_NMS 12000
#define POST_NMS 2000
#define NMS_WORDS 188            // ceil(12000/64)
#define CAND_MAX 16384
#define SORT_N 16384
#define NMS_TH 0.7f
#define MIN_SIZE_C 16.0f

// generate_anchors(16, (0.5,1,2), (8,16,32)) — classic py-faster-rcnn table
__constant__ float ANCH[NA][4] = {
  {-84.f,-40.f,99.f,55.f},
  {-176.f,-88.f,191.f,103.f},
  {-360.f,-184.f,375.f,199.f},
  {-56.f,-56.f,71.f,71.f},
  {-120.f,-120.f,135.f,135.f},
  {-248.f,-248.f,263.f,263.f},
  {-36.f,-80.f,51.f,95.f},
  {-80.f,-168.f,95.f,183.f},
  {-168.f,-344.f,183.f,359.f}
};

__device__ __forceinline__ void decode_box(int a, int h, int w,
    const float* __restrict__ deltas, float im_h, float im_w,
    float& x1, float& y1, float& x2, float& y2) {
  float sx = (float)(w * 16);
  float sy = (float)(h * 16);
  float ax1 = ANCH[a][0] + sx;
  float ay1 = ANCH[a][1] + sy;
  float ax2 = ANCH[a][2] + sx;
  float ay2 = ANCH[a][3] + sy;
  float aw = ax2 - ax1 + 1.0f;
  float ah = ay2 - ay1 + 1.0f;
  float acx = ax1 + 0.5f * aw;
  float acy = ay1 + 0.5f * ah;
  int base = h * FW + w;
  float d0 = deltas[(4*a+0)*HW + base];
  float d1 = deltas[(4*a+1)*HW + base];
  float d2 = deltas[(4*a+2)*HW + base];
  float d3 = deltas[(4*a+3)*HW + base];
  float pcx = d0 * aw + acx;
  float pcy = d1 * ah + acy;
  float pw = expf(d2) * aw;
  float ph = expf(d3) * ah;
  x1 = pcx - 0.5f * pw;
  y1 = pcy - 0.5f * ph;
  x2 = pcx + 0.5f * pw;
  y2 = pcy + 0.5f * ph;
  x1 = fminf(fmaxf(x1, 0.0f), im_w - 1.0f);
  x2 = fminf(fmaxf(x2, 0.0f), im_w - 1.0f);
  y1 = fminf(fmaxf(y1, 0.0f), im_h - 1.0f);
  y2 = fminf(fmaxf(y2, 0.0f), im_h - 1.0f);
}

// keys + level-0 (top byte) histogram. one thread per spatial pos, loop anchors.
__global__ void k_keys(const float* __restrict__ scores, const float* __restrict__ deltas,
                       const float* __restrict__ im_info, unsigned* __restrict__ keys,
                       unsigned* __restrict__ hist0) {
  __shared__ unsigned lh[256];
  int t = threadIdx.x;
  lh[t] = 0;
  __syncthreads();
  int base = blockIdx.x * blockDim.x + t;     // < HW by construction
  float im_h = im_info[0], im_w = im_info[1];
  float ms = MIN_SIZE_C * im_info[2];
  int h = base / FW, w = base % FW;
  for (int a = 0; a < NA; a++) {
    float x1, y1, x2, y2;
    decode_box(a, h, w, deltas, im_h, im_w, x1, y1, x2, y2);
    bool valid = ((x2 - x1 + 1.0f) >= ms) && ((y2 - y1 + 1.0f) >= ms);
    float sc = scores[(NA + a)*HW + base];
    float v = valid ? sc : -INFINITY;
    unsigned u = __float_as_uint(v);
    unsigned mono = (u & 0x80000000u) ? ~u : (u | 0x80000000u);
    keys[base*NA + a] = mono;
    atomicAdd(&lh[mono >> 24], 1u);
  }
  __syncthreads();
  atomicAdd(&hist0[t], lh[t]);
}

// find byte at `shift` s.t. suffix count crosses target. scal[0]=prefix acc, scal[1]=remaining target (0 sentinel = 12000)
__global__ void k_find(const unsigned* __restrict__ hist, unsigned* __restrict__ scal, int shift) {
  __shared__ unsigned ssum[256];
  int t = threadIdx.x;
  unsigned hv = hist[t];
  ssum[t] = hv;
  __syncthreads();
  for (int off = 1; off < 256; off <<= 1) {
    unsigned v = ssum[t];
    unsigned add = (t + off < 256) ? ssum[t + off] : 0u;
    __syncthreads();
    ssum[t] = v + add;
    __syncthreads();
  }
  unsigned acc_above = ssum[t] - hv;          // count of keys in bins > t
  unsigned target = scal[1];
  if (target == 0u) target = PRE_NMS;
  if (acc_above < target && acc_above + hv >= target) {
    scal[0] |= ((unsigned)t << shift);
    scal[1] = target - acc_above;
  }
}

// histogram next byte among keys matching current prefix
__global__ void k_refine(const unsigned* __restrict__ keys, const unsigned* __restrict__ scal,
                         unsigned* __restrict__ hist, int shift) {
  __shared__ unsigned lh[256];
  int t = threadIdx.x;
  lh[t] = 0;
  __syncthreads();
  unsigned prefix = scal[0] >> (shift + 8);
  int stride = gridDim.x * blockDim.x;
  for (int i = blockIdx.x * blockDim.x + t; i < TOTAL; i += stride) {
    unsigned k = keys[i];
    if ((k >> (shift + 8)) == prefix) atomicAdd(&lh[(k >> shift) & 0xFFu], 1u);
  }
  __syncthreads();
  atomicAdd(&hist[t], lh[t]);
}

__global__ void k_compact(const unsigned* __restrict__ keys, const unsigned* __restrict__ scal,
                          unsigned* __restrict__ cnt, unsigned long long* __restrict__ cand) {
  unsigned K = scal[0];
  int stride = gridDim.x * blockDim.x;
  for (int i = blockIdx.x * blockDim.x + threadIdx.x; i < TOTAL; i += stride) {
    unsigned k = keys[i];
    if (k >= K) {
      unsigned pos = atomicAdd(cnt, 1u);
      if (pos < CAND_MAX)
        cand[pos] = ((unsigned long long)k << 32) | (unsigned)(~(unsigned)i);
    }
  }
}

// single-block bitonic sort, descending, of 16384 composites in 128 KiB dynamic LDS.
// composite = (mono<<32) | ~idx  -> descending sort == top_k (value desc, index asc)
__global__ void __launch_bounds__(1024) k_sort(const unsigned* __restrict__ scal,
    const unsigned long long* __restrict__ cand, unsigned long long* __restrict__ topk) {
  extern __shared__ unsigned long long sh[];
  int t = threadIdx.x;
  unsigned cnt = scal[4];
  if (cnt > CAND_MAX) cnt = CAND_MAX;
  for (int i = t; i < SORT_N; i += 1024) sh[i] = (i < (int)cnt) ? cand[i] : 0ULL;
  for (unsigned kk = 2; kk <= SORT_N; kk <<= 1) {
    for (unsigned j = kk >> 1; j > 0; j >>= 1) {
      __syncthreads();
      for (unsigned i = t; i < SORT_N; i += 1024) {
        unsigned ixj = i ^ j;
        if (ixj > i) {
          unsigned long long a = sh[i], b = sh[ixj];
          bool up = ((i & kk) == 0);
          if (up ? (a < b) : (a > b)) { sh[i] = b; sh[ixj] = a; }
        }
      }
    }
  }
  __syncthreads();
  for (int i = t; i < PRE_NMS; i += 1024) topk[i] = sh[i];
}

__global__ void k_decode_top(const unsigned long long* __restrict__ topk,
    const float* __restrict__ deltas, const float* __restrict__ im_info,
    float4* __restrict__ boxes, float* __restrict__ scoresArr,
    unsigned long long* __restrict__ remv) {
  int r = blockIdx.x * blockDim.x + threadIdx.x;
  if (r >= PRE_NMS) return;
  unsigned long long c = topk[r];
  unsigned mono = (unsigned)(c >> 32);
  unsigned idx = ~(unsigned)(c & 0xFFFFFFFFull);
  unsigned u = (mono & 0x80000000u) ? (mono ^ 0x80000000u) : ~mono;
  float sc = __uint_as_float(u);
  int a = idx % NA;
  int base = idx / NA;
  int h = base / FW, w = base % FW;
  float x1, y1, x2, y2;
  decode_box(a, h, w, deltas, im_info[0], im_info[1], x1, y1, x2, y2);
  boxes[r] = make_float4(x1, y1, x2, y2);
  scoresArr[r] = sc;
  if (!(sc > -INFINITY)) atomicOr(&remv[r >> 6], 1ULL << (r & 63));  // invalid -> never kept
}

// 64x64 suppression tiles; only upper triangle (bj>=bi). lower-triangle words stay
// poisoned, which is harmless: those column decisions happen before any OR of this row.
__global__ void k_mask(const float4* __restrict__ boxes, unsigned long long* __restrict__ mask) {
  int bi = blockIdx.y, bj = blockIdx.x;
  if (bj < bi) return;
  __shared__ float4 jb[64];
  int t = threadIdx.x;
  int jg = bj * 64 + t;
  jb[t] = (jg < PRE_NMS) ? boxes[jg] : make_float4(0.f, 0.f, -1.f, -1.f);
  __syncthreads();
  int i = bi * 64 + t;
  if (i >= PRE_NMS) return;
  float4 b = boxes[i];
  float area_i = (b.z - b.x + 1.0f) * (b.w - b.y + 1.0f);
  unsigned long long bits = 0;
  for (int jj = 0; jj < 64; jj++) {
    float4 o = jb[jj];
    float xx1 = fmaxf(b.x, o.x);
    float yy1 = fmaxf(b.y, o.y);
    float xx2 = fminf(b.z, o.z);
    float yy2 = fminf(b.w, o.w);
    float iw = fmaxf(xx2 - xx1 + 1.0f, 0.0f);
    float ih = fmaxf(yy2 - yy1 + 1.0f, 0.0f);
    float inter = iw * ih;
    float area_o = (o.z - o.x + 1.0f) * (o.w - o.y + 1.0f);
    float iou = inter / (area_i + area_o - inter);
    if (iou > NMS_TH) bits |= (1ULL << jj);
  }
  mask[(size_t)i * NMS_WORDS + bj] = bits;
}

// single-wave chunked greedy NMS with early exit at POST_NMS kept.
__global__ void k_nms(const unsigned long long* __restrict__ mask,
                      const unsigned long long* __restrict__ remv_init,
                      unsigned* __restrict__ kept, unsigned* __restrict__ scal) {
  int lane = threadIdx.x;  // 64
  __shared__ unsigned klist[POST_NMS];
  unsigned long long r0 = remv_init[lane];
  unsigned long long r1 = remv_init[64 + lane];
  unsigned long long r2 = (lane < NMS_WORDS - 128) ? remv_init[128 + lane] : ~0ULL;
  int kept_cnt = 0;
  for (int c = 0; c < NMS_WORDS; c++) {
    int owner = c & 63;
    int slot = c >> 6;
    unsigned long long myw = (slot == 0) ? r0 : ((slot == 1) ? r1 : r2);
    unsigned long long rw = __shfl(myw, owner);
    int gi0 = c * 64;
    int gl = gi0 + lane;
    unsigned long long diag = (gl < PRE_NMS) ? mask[(size_t)gl * NMS_WORDS + c] : 0ULL;
    int jmax = PRE_NMS - gi0; if (jmax > 64) jmax = 64;
    for (int j = 0; j < jmax; j++) {
      if (!((rw >> j) & 1ULL)) {
        if (lane == 0) klist[kept_cnt] = (unsigned)(gi0 + j);
        kept_cnt++;
        rw |= __shfl(diag, j);
        size_t rb = (size_t)(gi0 + j) * NMS_WORDS;
        r0 |= mask[rb + lane];
        r1 |= mask[rb + 64 + lane];
        if (lane < NMS_WORDS - 128) r2 |= mask[rb + 128 + lane];
        if (kept_cnt >= POST_NMS) break;
      }
    }
    if (kept_cnt >= POST_NMS) break;
  }
  __syncthreads();
  if (lane == 0) scal[5] = (unsigned)kept_cnt;
  for (int s = lane; s < kept_cnt; s += 64) kept[s] = klist[s];
}

__global__ void k_out(const unsigned* __restrict__ scal, const unsigned* __restrict__ kept,
                      const float4* __restrict__ boxes, const float* __restrict__ scoresArr,
                      float* __restrict__ out) {
  int s = blockIdx.x * blockDim.x + threadIdx.x;
  if (s >= POST_NMS) return;
  unsigned cnt = scal[5];
  float x1 = 0.f, y1 = 0.f, x2 = 0.f, y2 = 0.f, sc = 0.f;
  if (s < (int)cnt) {
    unsigned r = kept[s];
    float4 b = boxes[r];
    x1 = b.x; y1 = b.y; x2 = b.z; y2 = b.w;
    sc = scoresArr[r];
  }
  out[s*5 + 0] = 0.f;
  out[s*5 + 1] = x1;
  out[s*5 + 2] = y1;
  out[s*5 + 3] = x2;
  out[s*5 + 4] = y2;
  out[POST_NMS*5 + s] = sc;
}

extern "C" void kernel_launch(void* const* d_in, const int* in_sizes, int n_in,
                              void* d_out, int out_size, void* d_ws, size_t ws_size,
                              hipStream_t stream) {
  const float* scores  = (const float*)d_in[0];
  const float* deltas  = (const float*)d_in[1];
  const float* im_info = (const float*)d_in[2];
  float* out = (float*)d_out;
  char* ws = (char*)d_ws;

  // workspace layout (bytes)
  unsigned* keys             = (unsigned*)(ws + 0);                 //  9,437,184
  unsigned* hist4            = (unsigned*)(ws + 9437184);           //  4*256*4 = 4096
  unsigned* scal             = (unsigned*)(ws + 9441280);           //  256
  unsigned long long* remv   = (unsigned long long*)(ws + 9441536); //  1536
  unsigned long long* cand   = (unsigned long long*)(ws + 9443072); //  131072
  unsigned long long* topk   = (unsigned long long*)(ws + 9574144); //  96256
  float4* boxes              = (float4*)(ws + 9670400);             //  192000
  float* scoresArr           = (float*)(ws + 9862400);              //  48128
  unsigned* kept             = (unsigned*)(ws + 9910528);           //  8192
  unsigned long long* mask   = (unsigned long long*)(ws + 9918720); //  18,048,000 -> total ~26.7 MB

  // zero hists + scalars + remv_init
  hipMemsetAsync(ws + 9437184, 0, 4096 + 256 + 1536, stream);

  k_keys<<<HW/256, 256, 0, stream>>>(scores, deltas, im_info, keys, hist4);
  k_find<<<1, 256, 0, stream>>>(hist4, scal, 24);
  k_refine<<<2048, 256, 0, stream>>>(keys, scal, hist4 + 256, 16);
  k_find<<<1, 256, 0, stream>>>(hist4 + 256, scal, 16);
  k_refine<<<2048, 256, 0, stream>>>(keys, scal, hist4 + 512, 8);
  k_find<<<1, 256, 0, stream>>>(hist4 + 512, scal, 8);
  k_refine<<<2048, 256, 0, stream>>>(keys, scal, hist4 + 768, 0);
  k_find<<<1, 256, 0, stream>>>(hist4 + 768, scal, 0);
  k_compact<<<2048, 256, 0, stream>>>(keys, scal, &scal[4], cand);

  (void)hipFuncSetAttribute((const void*)k_sort,
        hipFuncAttributeMaxDynamicSharedMemorySize, SORT_N * 8);
  k_sort<<<1, 1024, SORT_N * 8, stream>>>(scal, cand, topk);

  k_decode_top<<<(PRE_NMS + 255)/256, 256, 0, stream>>>(topk, deltas, im_info, boxes, scoresArr, remv);

  dim3 mg(NMS_WORDS, NMS_WORDS);
  k_mask<<<mg, 64, 0, stream>>>(boxes, mask);
  k_nms<<<1, 64, 0, stream>>>(mask, remv, kept, scal);
  k_out<<<(POST_NMS + 255)/256, 256, 0, stream>>>(scal, kept, boxes, scoresArr, out);
}

// Round 2
// 1161.392 us; speedup vs baseline: 1.2328x; 1.2328x over previous
//
#include <hip/hip_runtime.h>
#include <hip/hip_bf16.h>
#include <stdint.h>

#pragma clang fp contract(off)

#define FH 512
#define FW 512
#define NA 9
#define HW (FH*FW)
#define TOTAL (HW*NA)
#define PRE_NMS 12000
#define POST_NMS 2000
#define NMS_WORDS 188            // ceil(12000/64)
#define CAND_MAX 16384
#define NMS_TH 0.7f
#define MIN_SIZE_C 16.0f

// generate_anchors(16, (0.5,1,2), (8,16,32)) — classic py-faster-rcnn table
__constant__ float ANCH[NA][4] = {
  {-84.f,-40.f,99.f,55.f},
  {-176.f,-88.f,191.f,103.f},
  {-360.f,-184.f,375.f,199.f},
  {-56.f,-56.f,71.f,71.f},
  {-120.f,-120.f,135.f,135.f},
  {-248.f,-248.f,263.f,263.f},
  {-36.f,-80.f,51.f,95.f},
  {-80.f,-168.f,95.f,183.f},
  {-168.f,-344.f,183.f,359.f}
};

__device__ __forceinline__ void decode_box(int a, int h, int w,
    const float* __restrict__ deltas, float im_h, float im_w,
    float& x1, float& y1, float& x2, float& y2) {
  float sx = (float)(w * 16);
  float sy = (float)(h * 16);
  float ax1 = ANCH[a][0] + sx;
  float ay1 = ANCH[a][1] + sy;
  float ax2 = ANCH[a][2] + sx;
  float ay2 = ANCH[a][3] + sy;
  float aw = ax2 - ax1 + 1.0f;
  float ah = ay2 - ay1 + 1.0f;
  float acx = ax1 + 0.5f * aw;
  float acy = ay1 + 0.5f * ah;
  int base = h * FW + w;
  float d0 = deltas[(4*a+0)*HW + base];
  float d1 = deltas[(4*a+1)*HW + base];
  float d2 = deltas[(4*a+2)*HW + base];
  float d3 = deltas[(4*a+3)*HW + base];
  float pcx = d0 * aw + acx;
  float pcy = d1 * ah + acy;
  float pw = expf(d2) * aw;
  float ph = expf(d3) * ah;
  x1 = pcx - 0.5f * pw;
  y1 = pcy - 0.5f * ph;
  x2 = pcx + 0.5f * pw;
  y2 = pcy + 0.5f * ph;
  x1 = fminf(fmaxf(x1, 0.0f), im_w - 1.0f);
  x2 = fminf(fmaxf(x2, 0.0f), im_w - 1.0f);
  y1 = fminf(fmaxf(y1, 0.0f), im_h - 1.0f);
  y2 = fminf(fmaxf(y2, 0.0f), im_h - 1.0f);
}

// keys + level-0 (top byte) histogram. one thread per spatial pos, loop anchors.
__global__ void k_keys(const float* __restrict__ scores, const float* __restrict__ deltas,
                       const float* __restrict__ im_info, unsigned* __restrict__ keys,
                       unsigned* __restrict__ hist0) {
  __shared__ unsigned lh[256];
  int t = threadIdx.x;
  lh[t] = 0;
  __syncthreads();
  int base = blockIdx.x * blockDim.x + t;     // < HW by construction
  float im_h = im_info[0], im_w = im_info[1];
  float ms = MIN_SIZE_C * im_info[2];
  int h = base / FW, w = base % FW;
  for (int a = 0; a < NA; a++) {
    float x1, y1, x2, y2;
    decode_box(a, h, w, deltas, im_h, im_w, x1, y1, x2, y2);
    bool valid = ((x2 - x1 + 1.0f) >= ms) && ((y2 - y1 + 1.0f) >= ms);
    float sc = scores[(NA + a)*HW + base];
    float v = valid ? sc : -INFINITY;
    unsigned u = __float_as_uint(v);
    unsigned mono = (u & 0x80000000u) ? ~u : (u | 0x80000000u);
    keys[base*NA + a] = mono;
    atomicAdd(&lh[mono >> 24], 1u);
  }
  __syncthreads();
  atomicAdd(&hist0[t], lh[t]);
}

// find byte at `shift` s.t. suffix count crosses target. scal[0]=prefix acc, scal[1]=remaining target (0 sentinel = 12000)
__global__ void k_find(const unsigned* __restrict__ hist, unsigned* __restrict__ scal, int shift) {
  __shared__ unsigned ssum[256];
  int t = threadIdx.x;
  unsigned hv = hist[t];
  ssum[t] = hv;
  __syncthreads();
  for (int off = 1; off < 256; off <<= 1) {
    unsigned v = ssum[t];
    unsigned add = (t + off < 256) ? ssum[t + off] : 0u;
    __syncthreads();
    ssum[t] = v + add;
    __syncthreads();
  }
  unsigned acc_above = ssum[t] - hv;          // count of keys in bins > t
  unsigned target = scal[1];
  if (target == 0u) target = PRE_NMS;
  if (acc_above < target && acc_above + hv >= target) {
    scal[0] |= ((unsigned)t << shift);
    scal[1] = target - acc_above;
  }
}

// histogram next byte among keys matching current prefix
__global__ void k_refine(const unsigned* __restrict__ keys, const unsigned* __restrict__ scal,
                         unsigned* __restrict__ hist, int shift) {
  __shared__ unsigned lh[256];
  int t = threadIdx.x;
  lh[t] = 0;
  __syncthreads();
  unsigned prefix = scal[0] >> (shift + 8);
  int stride = gridDim.x * blockDim.x;
  for (int i = blockIdx.x * blockDim.x + t; i < TOTAL; i += stride) {
    unsigned k = keys[i];
    if ((k >> (shift + 8)) == prefix) atomicAdd(&lh[(k >> shift) & 0xFFu], 1u);
  }
  __syncthreads();
  atomicAdd(&hist[t], lh[t]);
}

__global__ void k_compact(const unsigned* __restrict__ keys, const unsigned* __restrict__ scal,
                          unsigned* __restrict__ cnt, unsigned long long* __restrict__ cand) {
  unsigned K = scal[0];
  int stride = gridDim.x * blockDim.x;
  for (int i = blockIdx.x * blockDim.x + threadIdx.x; i < TOTAL; i += stride) {
    unsigned k = keys[i];
    if (k >= K) {
      unsigned pos = atomicAdd(cnt, 1u);
      if (pos < CAND_MAX)
        cand[pos] = ((unsigned long long)k << 32) | (unsigned)(~(unsigned)i);
    }
  }
}

// O(N^2) exact rank: rank(i) = #{j : cand[j] > cand[i]}. Composite is unique,
// so ranks are a permutation; descending order == top_k (value desc, index asc).
// 64 blocks x 256 threads = 16384 = CAND_MAX -> each thread owns <=1 item.
__global__ void __launch_bounds__(256) k_rank(const unsigned* __restrict__ scal,
    const unsigned long long* __restrict__ cand, unsigned long long* __restrict__ topk) {
  __shared__ unsigned long long tile[2048];
  unsigned cnt = scal[4];
  if (cnt > CAND_MAX) cnt = CAND_MAX;
  int i = blockIdx.x * 256 + threadIdx.x;
  unsigned long long mine = (i < (int)cnt) ? cand[i] : 0ULL;
  int rank = 0;
  for (unsigned t0 = 0; t0 < cnt; t0 += 2048) {
    unsigned n = min(2048u, cnt - t0);
    __syncthreads();
    for (unsigned j = threadIdx.x; j < n; j += 256) tile[j] = cand[t0 + j];
    __syncthreads();
    if (i < (int)cnt) {
      unsigned j = 0;
      #pragma unroll 8
      for (; j < n; j++) rank += (tile[j] > mine) ? 1 : 0;
    }
  }
  if (i < (int)cnt && rank < PRE_NMS) topk[rank] = mine;
}

__global__ void k_decode_top(const unsigned long long* __restrict__ topk,
    const float* __restrict__ deltas, const float* __restrict__ im_info,
    float4* __restrict__ boxes, float* __restrict__ scoresArr,
    unsigned long long* __restrict__ remv) {
  int r = blockIdx.x * blockDim.x + threadIdx.x;
  if (r >= PRE_NMS) return;
  unsigned long long c = topk[r];
  unsigned mono = (unsigned)(c >> 32);
  unsigned idx = ~(unsigned)(c & 0xFFFFFFFFull);
  unsigned u = (mono & 0x80000000u) ? (mono ^ 0x80000000u) : ~mono;
  float sc = __uint_as_float(u);
  int a = idx % NA;
  int base = idx / NA;
  int h = base / FW, w = base % FW;
  float x1, y1, x2, y2;
  decode_box(a, h, w, deltas, im_info[0], im_info[1], x1, y1, x2, y2);
  boxes[r] = make_float4(x1, y1, x2, y2);
  scoresArr[r] = sc;
  if (!(sc > -INFINITY)) atomicOr(&remv[r >> 6], 1ULL << (r & 63));  // invalid -> never kept
}

// 64x64 suppression tiles; only upper triangle (bj>=bi). lower-triangle words stay
// poisoned, which is harmless: those column decisions happen before any OR of this row.
__global__ void k_mask(const float4* __restrict__ boxes, unsigned long long* __restrict__ mask) {
  int bi = blockIdx.y, bj = blockIdx.x;
  if (bj < bi) return;
  __shared__ float4 jb[64];
  int t = threadIdx.x;
  int jg = bj * 64 + t;
  jb[t] = (jg < PRE_NMS) ? boxes[jg] : make_float4(0.f, 0.f, -1.f, -1.f);
  __syncthreads();
  int i = bi * 64 + t;
  if (i >= PRE_NMS) return;
  float4 b = boxes[i];
  float area_i = (b.z - b.x + 1.0f) * (b.w - b.y + 1.0f);
  unsigned long long bits = 0;
  for (int jj = 0; jj < 64; jj++) {
    float4 o = jb[jj];
    float xx1 = fmaxf(b.x, o.x);
    float yy1 = fmaxf(b.y, o.y);
    float xx2 = fminf(b.z, o.z);
    float yy2 = fminf(b.w, o.w);
    float iw = fmaxf(xx2 - xx1 + 1.0f, 0.0f);
    float ih = fmaxf(yy2 - yy1 + 1.0f, 0.0f);
    float inter = iw * ih;
    float area_o = (o.z - o.x + 1.0f) * (o.w - o.y + 1.0f);
    float iou = inter / (area_i + area_o - inter);
    if (iou > NMS_TH) bits |= (1ULL << jj);
  }
  mask[(size_t)i * NMS_WORDS + bj] = bits;
}

// single-wave greedy NMS, chunked, with batched row-ORs.
// Phase 1 per chunk: resolve kept set entirely in-register (ffs-skip + shfl of the
// preloaded diagonal word per KEPT box only). Phase 2: OR kept rows into the remv
// registers with 8-row statically-unrolled load batches (one waitcnt per batch,
// 24 loads in flight) instead of one latency round-trip per kept box.
__global__ void k_nms(const unsigned long long* __restrict__ mask,
                      const unsigned long long* __restrict__ remv_init,
                      unsigned* __restrict__ kept, unsigned* __restrict__ scal) {
  int lane = threadIdx.x;  // 64
  __shared__ unsigned klist[POST_NMS];
  __shared__ int jls[64];
  unsigned long long r0 = remv_init[lane];
  unsigned long long r1 = remv_init[64 + lane];
  unsigned long long r2 = (lane < NMS_WORDS - 128) ? remv_init[128 + lane] : ~0ULL;
  int kept_cnt = 0;
  bool done = false;
  // prefetch chunk-0 diagonal word: mask[lane][0]
  unsigned long long diag = mask[(size_t)lane * NMS_WORDS + 0];
  for (int c = 0; c < NMS_WORDS; c++) {
    int owner = c & 63;
    int slot = c >> 6;
    unsigned long long myw = (slot == 0) ? r0 : ((slot == 1) ? r1 : r2);
    unsigned long long rw = __shfl(myw, owner);
    int gi0 = c * 64;
    int jmax = PRE_NMS - gi0; if (jmax > 64) jmax = 64;
    // ---- phase 1: in-register resolve ----
    unsigned long long avail = ~rw;
    if (jmax < 64) avail &= ((1ULL << jmax) - 1ULL);
    unsigned long long keptmask = 0;
    while (avail) {
      int j = __ffsll((long long)avail) - 1;
      keptmask |= (1ULL << j);
      if (lane == 0) klist[kept_cnt] = (unsigned)(gi0 + j);
      kept_cnt++;
      if (kept_cnt >= POST_NMS) { done = true; break; }
      unsigned long long supp = __shfl(diag, j);   // row (gi0+j)'s chunk-c word; self-bit set (IoU=1)
      avail &= ~supp;
      avail &= ~((1ULL << j) | ((1ULL << j) - 1ULL)); // ensure forward progress
    }
    if (done) break;
    // ---- prefetch next chunk's diagonal (overlaps phase 2) ----
    unsigned long long diag_next = 0;
    if (c + 1 < NMS_WORDS) {
      int gl = (c + 1) * 64 + lane;
      if (gl < PRE_NMS) diag_next = mask[(size_t)gl * NMS_WORDS + (c + 1)];
    }
    // ---- phase 2: batched row ORs ----
    if (keptmask) {
      // lanes cooperatively compact kept j's into LDS
      int myrank = __popcll(keptmask & ((lane == 0) ? 0ULL : ((1ULL << lane) - 1ULL)));
      if ((keptmask >> lane) & 1ULL) jls[myrank] = gi0 + lane;
      int njc = __popcll(keptmask);
      for (int b = 0; b < njc; b += 8) {
        unsigned long long v0[8], v1[8], v2[8];
        #pragma unroll
        for (int q = 0; q < 8; q++) {
          int jj = (b + q < njc) ? jls[b + q] : -1;
          if (jj >= 0) {
            size_t rb = (size_t)jj * NMS_WORDS;
            v0[q] = mask[rb + lane];
            v1[q] = mask[rb + 64 + lane];
            v2[q] = (lane < NMS_WORDS - 128) ? mask[rb + 128 + lane] : 0ULL;
          } else { v0[q] = 0; v1[q] = 0; v2[q] = 0; }
        }
        #pragma unroll
        for (int q = 0; q < 8; q++) { r0 |= v0[q]; r1 |= v1[q]; r2 |= v2[q]; }
      }
    }
    diag = diag_next;
  }
  __syncthreads();
  if (lane == 0) scal[5] = (unsigned)kept_cnt;
  for (int s = lane; s < kept_cnt; s += 64) kept[s] = klist[s];
}

__global__ void k_out(const unsigned* __restrict__ scal, const unsigned* __restrict__ kept,
                      const float4* __restrict__ boxes, const float* __restrict__ scoresArr,
                      float* __restrict__ out) {
  int s = blockIdx.x * blockDim.x + threadIdx.x;
  if (s >= POST_NMS) return;
  unsigned cnt = scal[5];
  float x1 = 0.f, y1 = 0.f, x2 = 0.f, y2 = 0.f, sc = 0.f;
  if (s < (int)cnt) {
    unsigned r = kept[s];
    float4 b = boxes[r];
    x1 = b.x; y1 = b.y; x2 = b.z; y2 = b.w;
    sc = scoresArr[r];
  }
  out[s*5 + 0] = 0.f;
  out[s*5 + 1] = x1;
  out[s*5 + 2] = y1;
  out[s*5 + 3] = x2;
  out[s*5 + 4] = y2;
  out[POST_NMS*5 + s] = sc;
}

extern "C" void kernel_launch(void* const* d_in, const int* in_sizes, int n_in,
                              void* d_out, int out_size, void* d_ws, size_t ws_size,
                              hipStream_t stream) {
  const float* scores  = (const float*)d_in[0];
  const float* deltas  = (const float*)d_in[1];
  const float* im_info = (const float*)d_in[2];
  float* out = (float*)d_out;
  char* ws = (char*)d_ws;

  // workspace layout (bytes)
  unsigned* keys             = (unsigned*)(ws + 0);                 //  9,437,184
  unsigned* hist4            = (unsigned*)(ws + 9437184);           //  4*256*4 = 4096
  unsigned* scal             = (unsigned*)(ws + 9441280);           //  256
  unsigned long long* remv   = (unsigned long long*)(ws + 9441536); //  1536
  unsigned long long* cand   = (unsigned long long*)(ws + 9443072); //  131072
  unsigned long long* topk   = (unsigned long long*)(ws + 9574144); //  96256
  float4* boxes              = (float4*)(ws + 9670400);             //  192000
  float* scoresArr           = (float*)(ws + 9862400);              //  48128
  unsigned* kept             = (unsigned*)(ws + 9910528);           //  8192
  unsigned long long* mask   = (unsigned long long*)(ws + 9918720); //  18,048,000 -> total ~26.7 MB

  // zero hists + scalars + remv_init
  hipMemsetAsync(ws + 9437184, 0, 4096 + 256 + 1536, stream);

  k_keys<<<HW/256, 256, 0, stream>>>(scores, deltas, im_info, keys, hist4);
  k_find<<<1, 256, 0, stream>>>(hist4, scal, 24);
  k_refine<<<2048, 256, 0, stream>>>(keys, scal, hist4 + 256, 16);
  k_find<<<1, 256, 0, stream>>>(hist4 + 256, scal, 16);
  k_refine<<<2048, 256, 0, stream>>>(keys, scal, hist4 + 512, 8);
  k_find<<<1, 256, 0, stream>>>(hist4 + 512, scal, 8);
  k_refine<<<2048, 256, 0, stream>>>(keys, scal, hist4 + 768, 0);
  k_find<<<1, 256, 0, stream>>>(hist4 + 768, scal, 0);
  k_compact<<<2048, 256, 0, stream>>>(keys, scal, &scal[4], cand);

  k_rank<<<CAND_MAX/256, 256, 0, stream>>>(scal, cand, topk);

  k_decode_top<<<(PRE_NMS + 255)/256, 256, 0, stream>>>(topk, deltas, im_info, boxes, scoresArr, remv);

  dim3 mg(NMS_WORDS, NMS_WORDS);
  k_mask<<<mg, 64, 0, stream>>>(boxes, mask);
  k_nms<<<1, 64, 0, stream>>>(mask, remv, kept, scal);
  k_out<<<(POST_NMS + 255)/256, 256, 0, stream>>>(scal, kept, boxes, scoresArr, out);
}

// Round 3
// 907.179 us; speedup vs baseline: 1.5782x; 1.2802x over previous
//
#include <hip/hip_runtime.h>
#include <hip/hip_bf16.h>
#include <stdint.h>

#pragma clang fp contract(off)

#define FH 512
#define FW 512
#define NA 9
#define HW (FH*FW)
#define TOTAL (HW*NA)
#define PRE_NMS 12000
#define POST_NMS 2000
#define NMS_WORDS 188            // ceil(12000/64)
#define MT 12032                 // padded row count per maskT slice (words)
#define CAND_MAX 16384
#define NMS_TH 0.7f
#define MIN_SIZE_C 16.0f

// generate_anchors(16, (0.5,1,2), (8,16,32)) — classic py-faster-rcnn table
__constant__ float ANCH[NA][4] = {
  {-84.f,-40.f,99.f,55.f},
  {-176.f,-88.f,191.f,103.f},
  {-360.f,-184.f,375.f,199.f},
  {-56.f,-56.f,71.f,71.f},
  {-120.f,-120.f,135.f,135.f},
  {-248.f,-248.f,263.f,263.f},
  {-36.f,-80.f,51.f,95.f},
  {-80.f,-168.f,95.f,183.f},
  {-168.f,-344.f,183.f,359.f}
};

__device__ __forceinline__ void decode_box(int a, int h, int w,
    const float* __restrict__ deltas, float im_h, float im_w,
    float& x1, float& y1, float& x2, float& y2) {
  float sx = (float)(w * 16);
  float sy = (float)(h * 16);
  float ax1 = ANCH[a][0] + sx;
  float ay1 = ANCH[a][1] + sy;
  float ax2 = ANCH[a][2] + sx;
  float ay2 = ANCH[a][3] + sy;
  float aw = ax2 - ax1 + 1.0f;
  float ah = ay2 - ay1 + 1.0f;
  float acx = ax1 + 0.5f * aw;
  float acy = ay1 + 0.5f * ah;
  int base = h * FW + w;
  float d0 = deltas[(4*a+0)*HW + base];
  float d1 = deltas[(4*a+1)*HW + base];
  float d2 = deltas[(4*a+2)*HW + base];
  float d3 = deltas[(4*a+3)*HW + base];
  float pcx = d0 * aw + acx;
  float pcy = d1 * ah + acy;
  float pw = expf(d2) * aw;
  float ph = expf(d3) * ah;
  x1 = pcx - 0.5f * pw;
  y1 = pcy - 0.5f * ph;
  x2 = pcx + 0.5f * pw;
  y2 = pcy + 0.5f * ph;
  x1 = fminf(fmaxf(x1, 0.0f), im_w - 1.0f);
  x2 = fminf(fmaxf(x2, 0.0f), im_w - 1.0f);
  y1 = fminf(fmaxf(y1, 0.0f), im_h - 1.0f);
  y2 = fminf(fmaxf(y2, 0.0f), im_h - 1.0f);
}

// keys + 8-bit (top byte) LDS-aggregated histogram.
__global__ void k_keys(const float* __restrict__ scores, const float* __restrict__ deltas,
                       const float* __restrict__ im_info, unsigned* __restrict__ keys,
                       unsigned* __restrict__ hist8) {
  __shared__ unsigned lh[256];
  int t = threadIdx.x;
  lh[t] = 0;
  __syncthreads();
  int base = blockIdx.x * blockDim.x + t;     // < HW by construction
  float im_h = im_info[0], im_w = im_info[1];
  float ms = MIN_SIZE_C * im_info[2];
  int h = base / FW, w = base % FW;
  for (int a = 0; a < NA; a++) {
    float x1, y1, x2, y2;
    decode_box(a, h, w, deltas, im_h, im_w, x1, y1, x2, y2);
    bool valid = ((x2 - x1 + 1.0f) >= ms) && ((y2 - y1 + 1.0f) >= ms);
    float sc = scores[(NA + a)*HW + base];
    float v = valid ? sc : -INFINITY;
    unsigned u = __float_as_uint(v);
    unsigned mono = (u & 0x80000000u) ? ~u : (u | 0x80000000u);
    keys[base*NA + a] = mono;
    atomicAdd(&lh[mono >> 24], 1u);
  }
  __syncthreads();
  atomicAdd(&hist8[t], lh[t]);
}

// per-block find8 (suffix scan of hist8) -> B8; histogram bits[23:9] of keys whose
// top byte == B8 into global hist15 (only ~50K elements -> cheap global atomics).
__global__ void __launch_bounds__(256) k_refine15(const unsigned* __restrict__ keys,
    const unsigned* __restrict__ hist8, unsigned* __restrict__ hist15) {
  __shared__ unsigned ssum[256];
  __shared__ unsigned sB8;
  int t = threadIdx.x;
  unsigned hv = hist8[t];
  ssum[t] = hv;
  __syncthreads();
  for (int off = 1; off < 256; off <<= 1) {
    unsigned v = ssum[t];
    unsigned add = (t + off < 256) ? ssum[t + off] : 0u;
    __syncthreads();
    ssum[t] = v + add;
    __syncthreads();
  }
  unsigned above = ssum[t] - hv;
  if (above < PRE_NMS && above + hv >= PRE_NMS) sB8 = (unsigned)t;
  __syncthreads();
  unsigned B8 = sB8;
  int stride = gridDim.x * blockDim.x;
  for (int i = blockIdx.x * blockDim.x + t; i < TOTAL; i += stride) {
    unsigned k = keys[i];
    if ((k >> 24) == B8) atomicAdd(&hist15[(k >> 9) & 0x7FFFu], 1u);
  }
}

// per-block find8 + find15 -> exact-bin threshold K; select keys >= K (<= ~12010 cands).
__global__ void __launch_bounds__(256) k_compact(const unsigned* __restrict__ keys,
    const unsigned* __restrict__ hist8, const unsigned* __restrict__ hist15,
    unsigned* __restrict__ cnt, unsigned long long* __restrict__ cand) {
  __shared__ unsigned ssum[256];
  __shared__ unsigned sB8, sT2, sB15;
  int t = threadIdx.x;
  // find8
  unsigned hv = hist8[t];
  ssum[t] = hv;
  __syncthreads();
  for (int off = 1; off < 256; off <<= 1) {
    unsigned v = ssum[t];
    unsigned add = (t + off < 256) ? ssum[t + off] : 0u;
    __syncthreads();
    ssum[t] = v + add;
    __syncthreads();
  }
  unsigned above = ssum[t] - hv;
  if (above < PRE_NMS && above + hv >= PRE_NMS) { sB8 = (unsigned)t; sT2 = PRE_NMS - above; }
  __syncthreads();
  unsigned B8 = sB8, T2 = sT2;
  // find15: thread t covers bins [t*128, t*128+128)
  unsigned loc = 0;
  for (int i = 0; i < 128; i++) loc += hist15[t*128 + i];
  __syncthreads();
  ssum[t] = loc;
  __syncthreads();
  for (int off = 1; off < 256; off <<= 1) {
    unsigned v = ssum[t];
    unsigned add = (t + off < 256) ? ssum[t + off] : 0u;
    __syncthreads();
    ssum[t] = v + add;
    __syncthreads();
  }
  unsigned above15 = ssum[t] - loc;         // count in bins above thread t's range
  unsigned acc = above15;
  for (int i = 127; i >= 0; i--) {
    unsigned cb = hist15[t*128 + i];
    acc += cb;
    if (acc >= T2 && acc - cb < T2) sB15 = (unsigned)(t*128 + i);
  }
  __syncthreads();
  unsigned K = (B8 << 24) | (sB15 << 9);
  int stride = gridDim.x * blockDim.x;
  for (int i = blockIdx.x * blockDim.x + t; i < TOTAL; i += stride) {
    unsigned k = keys[i];
    if (k >= K) {
      unsigned pos = atomicAdd(cnt, 1u);
      if (pos < CAND_MAX)
        cand[pos] = ((unsigned long long)k << 32) | (unsigned)(~(unsigned)i);
    }
  }
}

// O(N^2) exact rank over <= ~12010 cands; composite unique so ranks are a permutation;
// descending composite order == top_k (value desc, index asc). Thread with rank<12000
// also decodes its box + score (k_decode folded in).
__global__ void __launch_bounds__(256) k_rank(const unsigned* __restrict__ pcnt,
    const unsigned long long* __restrict__ cand,
    const float* __restrict__ deltas, const float* __restrict__ im_info,
    float4* __restrict__ boxes, float* __restrict__ scoresArr,
    unsigned long long* __restrict__ remvInit) {
  __shared__ unsigned long long tile[2048];
  unsigned cnt = *pcnt;
  if (cnt > CAND_MAX) cnt = CAND_MAX;
  int i = blockIdx.x * 256 + threadIdx.x;
  unsigned long long mine = (i < (int)cnt) ? cand[i] : 0ULL;
  int rank = 0;
  for (unsigned t0 = 0; t0 < cnt; t0 += 2048) {
    unsigned n = min(2048u, cnt - t0);
    __syncthreads();
    for (unsigned j = threadIdx.x; j < n; j += 256) tile[j] = cand[t0 + j];
    __syncthreads();
    if (i < (int)cnt) {
      unsigned j = 0;
      #pragma unroll 8
      for (; j < n; j++) rank += (tile[j] > mine) ? 1 : 0;
    }
  }
  if (i < (int)cnt && rank < PRE_NMS) {
    unsigned mono = (unsigned)(mine >> 32);
    unsigned idx = ~(unsigned)(mine & 0xFFFFFFFFull);
    unsigned u = (mono & 0x80000000u) ? (mono ^ 0x80000000u) : ~mono;
    float sc = __uint_as_float(u);
    int a = idx % NA;
    int base = idx / NA;
    int h = base / FW, w = base % FW;
    float x1, y1, x2, y2;
    decode_box(a, h, w, deltas, im_info[0], im_info[1], x1, y1, x2, y2);
    boxes[rank] = make_float4(x1, y1, x2, y2);
    scoresArr[rank] = sc;
    if (!(sc > -INFINITY)) atomicOr(&remvInit[rank >> 6], 1ULL << (rank & 63));
  }
}

// 64x64 suppression tiles, TRANSPOSED (chunk-major) store: maskT[word][row].
// Only upper triangle (bj>=bi) is written; that is exactly what k_nms reads.
__global__ void k_mask(const float4* __restrict__ boxes, unsigned long long* __restrict__ maskT) {
  int bi = blockIdx.y, bj = blockIdx.x;
  if (bj < bi) return;
  __shared__ float4 jb[64];
  int t = threadIdx.x;
  int jg = bj * 64 + t;
  jb[t] = (jg < PRE_NMS) ? boxes[jg] : make_float4(0.f, 0.f, -1.f, -1.f);
  __syncthreads();
  int i = bi * 64 + t;
  if (i >= PRE_NMS) return;
  float4 b = boxes[i];
  float area_i = (b.z - b.x + 1.0f) * (b.w - b.y + 1.0f);
  unsigned long long bits = 0;
  for (int jj = 0; jj < 64; jj++) {
    float4 o = jb[jj];
    float xx1 = fmaxf(b.x, o.x);
    float yy1 = fmaxf(b.y, o.y);
    float xx2 = fminf(b.z, o.z);
    float yy2 = fminf(b.w, o.w);
    float iw = fmaxf(xx2 - xx1 + 1.0f, 0.0f);
    float ih = fmaxf(yy2 - yy1 + 1.0f, 0.0f);
    float inter = iw * ih;
    float area_o = (o.z - o.x + 1.0f) * (o.w - o.y + 1.0f);
    float iou = inter / (area_i + area_o - inter);
    if (iou > NMS_TH) bits |= (1ULL << jj);
  }
  maskT[(size_t)bj * MT + i] = bits;    // coalesced across t
}

// single-wave greedy NMS, lazy word gather:
//   W_c = init[c] | OR_{kept j} maskT[c][j]
// Gather for chunk c+1 is DMA'd (global_load_lds, per-lane scattered src, zero VGPR
// cost -> full MLP) BEFORE resolving chunk c, so its latency hides under the serial
// resolve. Current chunk's new keeps contribute via the coalesced "next word" preload
// (nw) + masked wave-OR — no extra memory round trip on the critical path.
// Output writing (k_out) folded in.
__global__ void __launch_bounds__(64) k_nms(const unsigned long long* __restrict__ maskT,
    const unsigned long long* __restrict__ remvInit,
    const float4* __restrict__ boxes, const float* __restrict__ scoresArr,
    float* __restrict__ out) {
  int lane = threadIdx.x;  // 64
  __shared__ unsigned klist[POST_NMS];
  __shared__ unsigned long long gbuf[32 * 128];   // 32 issues x 64 lanes x 16B = 32KB
  int kept_cnt = 0;
  bool done = false;
  unsigned long long W = remvInit[0];
  unsigned long long diagc = maskT[lane];          // row lane, word 0
  unsigned long long nwc   = maskT[(size_t)MT + lane]; // row lane, word 1
  for (int c = 0; c < NMS_WORDS; c++) {
    bool more = (c + 1 < NMS_WORDS);
    int kc = kept_cnt;                  // kept from chunks < c
    int nIss = more ? ((kc + 63) >> 6) : 0;
    // A: issue gather DMAs for word (c+1) over klist[0..kc)
    for (int ii = 0; ii < nIss; ii++) {
      int q = ii * 64 + lane;
      if (q < kc) {
        unsigned j = klist[q];
        const void* g = (const void*)(maskT + (size_t)(c + 1) * MT + (j & ~1u));
        void* l = (void*)((char*)gbuf + ii * 1024);
        __builtin_amdgcn_global_load_lds(
            (const __attribute__((address_space(1))) unsigned*)g,
            (__attribute__((address_space(3))) unsigned*)l, 16, 0, 0);
      }
    }
    // B: prefetch next chunk's diag + next-word rows (coalesced)
    unsigned long long diagN = 0, nwN = 0;
    if (more) {
      diagN = maskT[(size_t)(c + 1) * MT + (c + 1) * 64 + lane];
      if (c + 2 < NMS_WORDS) nwN = maskT[(size_t)(c + 2) * MT + (c + 1) * 64 + lane];
    }
    // C: serial in-register resolve of chunk c (wave-uniform)
    int gi0 = c * 64;
    int jmax = PRE_NMS - gi0; if (jmax > 64) jmax = 64;
    unsigned long long avail = ~W;
    if (jmax < 64) avail &= ((1ULL << jmax) - 1ULL);
    unsigned long long keptmask = 0;
    while (avail) {
      int j = __ffsll((long long)avail) - 1;
      keptmask |= (1ULL << j);
      if (lane == 0) klist[kept_cnt] = (unsigned)(gi0 + j);
      kept_cnt++;
      if (kept_cnt >= POST_NMS) { done = true; break; }
      unsigned long long supp = __shfl(diagc, j);  // row (gi0+j)'s word c (self-bit set)
      avail &= ~supp;
      avail &= ~((2ULL << j) - 1ULL);              // clear bits <= j
    }
    if (done || !more) break;
    // D: this chunk's keeps contribute their word (c+1) via preloaded nw
    unsigned long long x = ((keptmask >> lane) & 1ULL) ? nwc : 0ULL;
    // E: drain DMAs, read back gather
    asm volatile("s_waitcnt vmcnt(0)" ::: "memory");
    for (int ii = 0; ii < nIss; ii++) {
      int q = ii * 64 + lane;
      if (q < kc) {
        unsigned j = klist[q];
        x |= gbuf[ii * 128 + lane * 2 + (j & 1u)];
      }
    }
    // F: wave OR-reduce -> W_{c+1}
    for (int off = 32; off; off >>= 1) x |= __shfl_xor(x, off);
    W = x | remvInit[c + 1];
    __syncthreads();   // klist visibility for next iteration's A
    diagc = diagN; nwc = nwN;
  }
  __syncthreads();
  // output (k_out folded in): rois + scores, zero-filled past kept_cnt
  for (int s = lane; s < POST_NMS; s += 64) {
    float x1 = 0.f, y1 = 0.f, x2 = 0.f, y2 = 0.f, sc = 0.f;
    if (s < kept_cnt) {
      unsigned r = klist[s];
      float4 b = boxes[r];
      x1 = b.x; y1 = b.y; x2 = b.z; y2 = b.w;
      sc = scoresArr[r];
    }
    out[s*5 + 0] = 0.f;
    out[s*5 + 1] = x1;
    out[s*5 + 2] = y1;
    out[s*5 + 3] = x2;
    out[s*5 + 4] = y2;
    out[POST_NMS*5 + s] = sc;
  }
}

extern "C" void kernel_launch(void* const* d_in, const int* in_sizes, int n_in,
                              void* d_out, int out_size, void* d_ws, size_t ws_size,
                              hipStream_t stream) {
  const float* scores  = (const float*)d_in[0];
  const float* deltas  = (const float*)d_in[1];
  const float* im_info = (const float*)d_in[2];
  float* out = (float*)d_out;
  char* ws = (char*)d_ws;

  // workspace layout (bytes)
  unsigned* keys             = (unsigned*)(ws + 0);                 //  9,437,184
  unsigned* hist8            = (unsigned*)(ws + 9437184);           //  1,024
  unsigned* hist15           = (unsigned*)(ws + 9438208);           //  131,072
  unsigned* scal             = (unsigned*)(ws + 9569280);           //  256
  unsigned long long* remvI  = (unsigned long long*)(ws + 9569536); //  1,536
  unsigned long long* cand   = (unsigned long long*)(ws + 9571072); //  131,072
  float4* boxes              = (float4*)(ws + 9702144);             //  192,000
  float* scoresArr           = (float*)(ws + 9894144);              //  48,000
  unsigned long long* maskT  = (unsigned long long*)(ws + 9942144); //  18,096,128 -> total ~28.0 MB

  // zero hist8 + hist15 + scal + remvInit in one shot
  hipMemsetAsync(ws + 9437184, 0, 133888, stream);

  k_keys<<<HW/256, 256, 0, stream>>>(scores, deltas, im_info, keys, hist8);
  k_refine15<<<256, 256, 0, stream>>>(keys, hist8, hist15);
  k_compact<<<256, 256, 0, stream>>>(keys, hist8, hist15, &scal[4], cand);
  k_rank<<<CAND_MAX/256, 256, 0, stream>>>(&scal[4], cand, deltas, im_info,
                                           boxes, scoresArr, remvI);
  dim3 mg(NMS_WORDS, NMS_WORDS);
  k_mask<<<mg, 64, 0, stream>>>(boxes, maskT);
  k_nms<<<1, 64, 0, stream>>>(maskT, remvI, boxes, scoresArr, out);
}